// Round 8
// baseline (686.664 us; speedup 1.0000x reference)
//
#include <hip/hip_runtime.h>
#include <cstdint>
#include <cstddef>

#define Dm 512
#define Sm 512
#define Bm 8
#define Hm 8
#define Fm 2048
#define Mm 4096   // B*S
#define Lm 4

typedef __bf16 bf16x8 __attribute__((ext_vector_type(8)));
typedef float  fx4    __attribute__((ext_vector_type(4)));
typedef float  fx2    __attribute__((ext_vector_type(2)));
typedef unsigned short u16;
typedef unsigned short u16x4 __attribute__((ext_vector_type(4)));
typedef short s16x8 __attribute__((ext_vector_type(8)));

__device__ __forceinline__ u16 f2b(float f) {
  union { float f; uint32_t u; } v; v.f = f;
  uint32_t u = v.u;
  return (u16)((u + 0x7fffu + ((u >> 16) & 1u)) >> 16);  // RNE
}
__device__ __forceinline__ float b2f(u16 h) {
  union { uint32_t u; float f; } v; v.u = ((uint32_t)h) << 16;
  return v.f;
}

__device__ __forceinline__ void gload16(const void* g, void* l) {
  __builtin_amdgcn_global_load_lds(
      (const __attribute__((address_space(1))) void*)g,
      (__attribute__((address_space(3))) void*)l, 16, 0, 0);
}

// counted vmcnt wait (immediate must be a literal) — T4
template<int N>
__device__ __forceinline__ void vwait() {
  if constexpr (N == 4)       asm volatile("s_waitcnt vmcnt(4)" ::: "memory");
  else if constexpr (N == 6)  asm volatile("s_waitcnt vmcnt(6)" ::: "memory");
  else if constexpr (N == 8)  asm volatile("s_waitcnt vmcnt(8)" ::: "memory");
  else if constexpr (N == 12) asm volatile("s_waitcnt vmcnt(12)" ::: "memory");
  else                        asm volatile("s_waitcnt vmcnt(0)" ::: "memory");
}

// ---------------- elementwise ----------------
__global__ void cast_bf16_kernel(const float* __restrict__ in, u16* __restrict__ out,
                                 u16* __restrict__ zpad) {
  int i = (blockIdx.x * 256 + threadIdx.x) * 4;
  fx4 v = *(const fx4*)(in + i);
  u16x4 o;
  #pragma unroll
  for (int j = 0; j < 4; ++j) o[j] = f2b(v[j]);
  *(u16x4*)(out + i) = o;
  if (blockIdx.x == 0) { zpad[threadIdx.x] = 0; zpad[threadIdx.x + 256] = 0; }
}

__global__ void avg3_kernel(const u16* __restrict__ o3, u16* __restrict__ out) {
  int i = (blockIdx.x * 256 + threadIdx.x) * 4;
  u16x4 a = *(const u16x4*)(o3 + i);
  u16x4 b = *(const u16x4*)(o3 + (size_t)Mm*Dm + i);
  u16x4 c = *(const u16x4*)(o3 + (size_t)2*Mm*Dm + i);
  u16x4 r;
  #pragma unroll
  for (int j = 0; j < 4; ++j)
    r[j] = f2b((b2f(a[j]) + b2f(b[j]) + b2f(c[j])) * (1.f/3.f));
  *(u16x4*)(out + i) = r;
}

// ---------------- layernorm (1 wave / row); in2 optional second addend ----------------
__global__ void ln_kernel(const float* __restrict__ in, const float* __restrict__ in2,
                          const float* __restrict__ gam, const float* __restrict__ bet,
                          float* __restrict__ outf, u16* __restrict__ outb) {
  int row = blockIdx.x;
  int t = threadIdx.x;  // 64
  const float* x = in + (size_t)row * Dm;
  fx4 v0 = *(const fx4*)(x + t*4);
  fx4 v1 = *(const fx4*)(x + 256 + t*4);
  if (in2) {
    const float* x2 = in2 + (size_t)row * Dm;
    fx4 w0 = *(const fx4*)(x2 + t*4);
    fx4 w1 = *(const fx4*)(x2 + 256 + t*4);
    #pragma unroll
    for (int j = 0; j < 4; ++j) { v0[j] += w0[j]; v1[j] += w1[j]; }
  }
  float s = 0.f, sq = 0.f;
  #pragma unroll
  for (int j = 0; j < 4; ++j) { s += v0[j] + v1[j]; sq += v0[j]*v0[j] + v1[j]*v1[j]; }
  #pragma unroll
  for (int off = 1; off < 64; off <<= 1) { s += __shfl_xor(s, off, 64); sq += __shfl_xor(sq, off, 64); }
  float mu  = s * (1.f/Dm);
  float var = sq * (1.f/Dm) - mu*mu;
  float rstd = rsqrtf(var + 1e-6f);
  fx4 g0 = *(const fx4*)(gam + t*4), g1 = *(const fx4*)(gam + 256 + t*4);
  fx4 b0 = *(const fx4*)(bet + t*4), b1 = *(const fx4*)(bet + 256 + t*4);
  float* of = outf + (size_t)row*Dm;
  u16*   ob = outb + (size_t)row*Dm;
  fx4 y0, y1; u16x4 h0, h1;
  #pragma unroll
  for (int j = 0; j < 4; ++j) {
    y0[j] = (v0[j]-mu)*rstd*g0[j] + b0[j];
    y1[j] = (v1[j]-mu)*rstd*g1[j] + b1[j];
    h0[j] = f2b(y0[j]); h1[j] = f2b(y1[j]);
  }
  *(fx4*)(of + t*4) = y0; *(fx4*)(of + 256 + t*4) = y1;
  *(u16x4*)(ob + t*4) = h0; *(u16x4*)(ob + 256 + t*4) = h1;
}

// ---------------- weight prep: fp32 [K][N] -> bf16 pre-swizzled 128x64 fragment-tile images
#define TST 130
__global__ void prep_kernel(u16* __restrict__ packed,
    const float* __restrict__ Wq1, const float* __restrict__ Wq3, const float* __restrict__ Wq5,
    const float* __restrict__ Wk1, const float* __restrict__ Wk3, const float* __restrict__ Wk5,
    const float* __restrict__ Wv,  const float* __restrict__ Wo,
    const float* __restrict__ W1,  const float* __restrict__ W2, int layer) {
  __shared__ float T[64 * TST];
  constexpr int t0[13] = {0,32,128,288,320,416,576,608,640,672,704,832,960};
  int bid = blockIdx.x;
  int seg = 0;
  while (bid >= t0[seg+1]) ++seg;
  int local = bid - t0[seg];
  const float* src; int K, N;
  switch (seg) {
    case 0:  src = Wq1 + (size_t)layer*512*512;   K = 512;  N = 512;  break;
    case 1:  src = Wq3 + (size_t)layer*3*512*512; K = 1536; N = 512;  break;
    case 2:  src = Wq5 + (size_t)layer*5*512*512; K = 2560; N = 512;  break;
    case 3:  src = Wk1 + (size_t)layer*512*512;   K = 512;  N = 512;  break;
    case 4:  src = Wk3 + (size_t)layer*3*512*512; K = 1536; N = 512;  break;
    case 5:  src = Wk5 + (size_t)layer*5*512*512; K = 2560; N = 512;  break;
    case 6:  src = Wv + (size_t)(layer*3+0)*512*512; K = 512; N = 512; break;
    case 7:  src = Wv + (size_t)(layer*3+1)*512*512; K = 512; N = 512; break;
    case 8:  src = Wv + (size_t)(layer*3+2)*512*512; K = 512; N = 512; break;
    case 9:  src = Wo + (size_t)layer*512*512;    K = 512;  N = 512;  break;
    case 10: src = W1 + (size_t)layer*512*2048;   K = 512;  N = 2048; break;
    default: src = W2 + (size_t)layer*2048*512;   K = 2048; N = 512;  break;
  }
  int KT = K >> 6;
  int ntile = local / KT, ktile = local - ntile*KT;
  const float* sb = src + (size_t)(ktile*64)*N + ntile*128;
  int tid = threadIdx.x;
  #pragma unroll
  for (int i = 0; i < 16; ++i) {                 // 4096 float2 chunks, coalesced
    int idx = i*256 + tid;
    int row = idx >> 6, col2 = (idx & 63) * 2;
    fx2 v = *(const fx2*)(sb + (size_t)row*N + col2);
    *(fx2*)(&T[row*TST + col2]) = v;
  }
  __syncthreads();
  u16* dst = packed + ((size_t)bid << 13);
  #pragma unroll
  for (int j = 0; j < 4; ++j) {
    int z = j*256 + tid;
    int row = z >> 3;
    int c = (z & 7) ^ (row & 7);
    s16x8 o;
    #pragma unroll
    for (int e = 0; e < 8; ++e) o[e] = (short)f2b(T[(c*8 + e)*TST + row]);
    *(s16x8*)(dst + z*8) = o;
  }
}

// ---------------- conv_all: heaviest-first 1D grid, counted-vmcnt pipeline (T4+T5) --------
// grid 1152. BM=128, BN=128, BK=64. A dbuf in LDS; B fragments direct from global.
// Raw s_barrier + vmcnt(12) keeps next tile's A-DMA in flight across the barrier.
__global__ __launch_bounds__(256, 3) void conv_all(const u16* __restrict__ xb,
    const u16* __restrict__ packed,
    const float* __restrict__ bq, const float* __restrict__ bk, const float* __restrict__ bv,
    u16* __restrict__ qb, u16* __restrict__ kb, u16* __restrict__ vT, int layer,
    const u16* __restrict__ zpad) {
  __shared__ __align__(16) u16 As[2][8192];
  constexpr int t0c[9]   = {0,32,128,288,320,416,576,608,640};
  constexpr int tapsc[9] = {1,3,5,1,3,5,1,1,1};
  constexpr int order[9] = {2,5,1,4,0,3,6,7,8};   // Q5,K5,Q3,K3,Q1,K1,V0,V1,V2
  int bid = blockIdx.x;
  int unit = order[bid >> 7];
  int local = bid & 127;
  int mtile = local >> 2, ntile = local & 3;
  int taps = tapsc[unit];
  int brow = mtile * 128, bcol = ntile * 128;
  int tid = threadIdx.x, lane = tid & 63, wid = tid >> 6;
  int wm = wid >> 1, wn = wid & 1;
  int r16 = lane & 15, g = lane >> 4;
  int tbase = t0c[unit] + ntile * taps * 8;
  fx4 acc[4][4] = {};
  int ntiles = taps * 8;
  int st = 0, skt = 0;
  auto stageA = [&](int bufi) {
    int shift = taps - 1 - st;
    int c0 = skt << 6;
    #pragma unroll
    for (int j = 0; j < 4; ++j) {        // A: 128x64 bf16, 4 DMA/thread
      int zb = wid*256 + j*64;
      int zz = zb + lane;
      int row = zz >> 3, c = (zz & 7) ^ (row & 7);
      int s = (brow + row) & (Sm - 1);
      const u16* src = (s >= shift) ? (xb + (size_t)(brow + row - shift)*Dm + c0 + c*8) : zpad;
      gload16(src, &As[bufi][zb * 8]);
    }
  };
  stageA(0);
  ++skt; if (skt == 8) { skt = 0; ++st; }
  __syncthreads();
  for (int idx = 0; idx < ntiles; ++idx) {
    int cur = idx & 1;
    const u16* wtc = packed + ((size_t)(tbase + idx) << 13);
    bf16x8 b[2][4];                      // 8 global loads
    #pragma unroll
    for (int kk = 0; kk < 2; ++kk)
      #pragma unroll
      for (int n = 0; n < 4; ++n) {
        int row = wn*64 + n*16 + r16;
        b[kk][n] = *(const bf16x8*)(wtc + (row << 6) + (((kk*4 + g) ^ (row & 7)) << 3));
      }
    bool staged = (idx + 1 < ntiles);
    if (staged) {
      stageA(cur ^ 1);                   // 4 DMA
      ++skt; if (skt == 8) { skt = 0; ++st; }
      vwait<12>();                       // drain prev tile's A-DMA only
    } else {
      vwait<8>();
    }
    bf16x8 a[2][4];
    #pragma unroll
    for (int kk = 0; kk < 2; ++kk)
      #pragma unroll
      for (int m = 0; m < 4; ++m) {
        int row = wm*64 + m*16 + r16;
        a[kk][m] = *(const bf16x8*)(&As[cur][(row << 6) + (((kk*4 + g) ^ (row & 7)) << 3)]);
      }
    __builtin_amdgcn_s_setprio(1);
    #pragma unroll
    for (int kk = 0; kk < 2; ++kk)
      #pragma unroll
      for (int m = 0; m < 4; ++m)
        #pragma unroll
        for (int n = 0; n < 4; ++n)
          acc[m][n] = __builtin_amdgcn_mfma_f32_16x16x32_bf16(a[kk][m], b[kk][n], acc[m][n], 0, 0, 0);
    __builtin_amdgcn_s_setprio(0);
    __builtin_amdgcn_s_barrier();        // raw: no vmcnt drain (ds/lgkm drained by MFMA use)
  }
  // epilogue (runtime branch, uniform per block)
  const float* bias; u16* outp;
  if (unit < 3)      { bias = bq + (size_t)(layer*3 + unit)*Dm;   outp = qb + (size_t)unit*Mm*Dm; }
  else if (unit < 6) { bias = bk + (size_t)(layer*3 + unit-3)*Dm; outp = kb + (size_t)(unit-3)*Mm*Dm; }
  else               { bias = bv + (size_t)(layer*3 + unit-6)*Dm; outp = vT + ((size_t)(unit-6) << 21); }
  if (unit < 6) {
    #pragma unroll
    for (int m = 0; m < 4; ++m) {
      int row0 = brow + wm*64 + m*16 + g*4;
      #pragma unroll
      for (int n = 0; n < 4; ++n) {
        int col = bcol + wn*64 + n*16 + r16;
        float bv_ = bias[col];
        #pragma unroll
        for (int r = 0; r < 4; ++r)
          outp[(size_t)(row0 + r)*Dm + col] = f2b(acc[m][n][r] + bv_);
      }
    }
  } else {
    #pragma unroll
    for (int m = 0; m < 4; ++m) {
      int row0 = brow + wm*64 + m*16 + g*4;
      int bidx = row0 >> 9, spos = row0 & 511;
      #pragma unroll
      for (int n = 0; n < 4; ++n) {
        int col = bcol + wn*64 + n*16 + r16;
        int hh = col >> 6, dd = col & 63;
        float bv_ = bias[col];
        u16x4 pk;
        #pragma unroll
        for (int r = 0; r < 4; ++r) pk[r] = f2b(acc[m][n][r] + bv_);
        *(u16x4*)(outp + (((size_t)(bidx*8 + hh)*64 + dd) << 9) + spos) = pk;
      }
    }
  }
}

// ---------------- unified GEMM core: A dbuf in LDS, B direct, counted-vmcnt (T4+T5) -------
// MODE 0: bf16 out; MODE 1: bf16 relu out; MODE 2: f32 out (+res if non-null)
template<int MODE, int BMt, int WN, bool CAUSAL>
__device__ __forceinline__ void gemm_core(const u16* __restrict__ A, int lda, int Ktap, int taps,
    const u16* __restrict__ Wt, const float* __restrict__ bias, const float* __restrict__ res,
    u16* __restrict__ outb, float* __restrict__ outf, int N, const u16* __restrict__ zpad,
    int ktN_stride, int ktile0) {
  constexpr int NR = 128 / (16 * WN);
  constexpr int BL = 2 * NR;      // B global loads / iter
  constexpr int AD = BMt / 32;    // A DMA issues / iter
  __shared__ __align__(16) u16 As[2][BMt * 64];
  int tid = threadIdx.x, lane = tid & 63, wid = tid >> 6;
  int wm = (WN == 2) ? (wid >> 1) : 0;
  int wn = (WN == 2) ? (wid & 1) : wid;
  int r16 = lane & 15, g = lane >> 4;
  int brow = blockIdx.x * BMt, bcol = blockIdx.y * 128;
  int KT = Ktap >> 6;
  const u16* WtN = Wt + ((size_t)(blockIdx.y * ktN_stride + ktile0) << 13);
  fx4 acc[4][NR] = {};
  int ntiles = taps * KT;
  int st = 0, skt = 0;
  auto stageA = [&](int bufi) {
    int shift = taps - 1 - st;
    int c0 = skt << 6;
    #pragma unroll
    for (int j = 0; j < AD; ++j) {
      int zb = wid*(BMt*2) + j*64;
      int zz = zb + lane;
      int row = zz >> 3, c = (zz & 7) ^ (row & 7);
      const u16* src;
      if (CAUSAL) {
        int s = (brow + row) & (Sm - 1);
        src = (s >= shift) ? (A + (size_t)(brow + row - shift)*lda + c0 + c*8) : zpad;
      } else {
        src = A + (size_t)(brow + row)*lda + c0 + c*8;
      }
      gload16(src, &As[bufi][zb * 8]);
    }
  };
  stageA(0);
  ++skt; if (skt == KT) { skt = 0; ++st; }
  __syncthreads();
  for (int idx = 0; idx < ntiles; ++idx) {
    int cur = idx & 1;
    const u16* wtc = WtN + ((size_t)idx << 13);
    bf16x8 b[2][NR];
    #pragma unroll
    for (int kk = 0; kk < 2; ++kk)
      #pragma unroll
      for (int n = 0; n < NR; ++n) {
        int row = wn*(NR*16) + n*16 + r16;
        b[kk][n] = *(const bf16x8*)(wtc + (row << 6) + (((kk*4 + g) ^ (row & 7)) << 3));
      }
    bool staged = (idx + 1 < ntiles);
    if (staged) {
      stageA(cur ^ 1);
      ++skt; if (skt == KT) { skt = 0; ++st; }
      vwait<BL + AD>();
    } else {
      vwait<BL>();
    }
    bf16x8 a[2][4];
    #pragma unroll
    for (int kk = 0; kk < 2; ++kk)
      #pragma unroll
      for (int m = 0; m < 4; ++m) {
        int row = wm*64 + m*16 + r16;
        a[kk][m] = *(const bf16x8*)(&As[cur][(row << 6) + (((kk*4 + g) ^ (row & 7)) << 3)]);
      }
    __builtin_amdgcn_s_setprio(1);
    #pragma unroll
    for (int kk = 0; kk < 2; ++kk)
      #pragma unroll
      for (int m = 0; m < 4; ++m)
        #pragma unroll
        for (int n = 0; n < NR; ++n)
          acc[m][n] = __builtin_amdgcn_mfma_f32_16x16x32_bf16(a[kk][m], b[kk][n], acc[m][n], 0, 0, 0);
    __builtin_amdgcn_s_setprio(0);
    __builtin_amdgcn_s_barrier();
  }
  #pragma unroll
  for (int m = 0; m < 4; ++m) {
    int row0 = brow + wm*64 + m*16 + g*4;
    #pragma unroll
    for (int n = 0; n < NR; ++n) {
      int col = bcol + wn*(NR*16) + n*16 + r16;
      float bv_ = bias[col];
      #pragma unroll
      for (int r = 0; r < 4; ++r) {
        size_t idx = (size_t)(row0 + r)*N + col;
        float v = acc[m][n][r] + bv_;
        if (MODE == 0)      outb[idx] = f2b(v);
        else if (MODE == 1) outb[idx] = f2b(fmaxf(v, 0.f));
        else                outf[idx] = v + (res ? res[idx] : 0.f);
      }
    }
  }
}

template<int MODE, int BMt, int WN, int LB>
__global__ __launch_bounds__(256, LB) void gemm_dense(const u16* __restrict__ A, int lda, int K,
    const u16* __restrict__ Wt, const float* __restrict__ bias, const float* __restrict__ res,
    u16* __restrict__ outb, float* __restrict__ outf, int N) {
  gemm_core<MODE, BMt, WN, false>(A, lda, K, 1, Wt, bias, res, outb, outf, N, nullptr, K >> 6, 0);
}

// ---------------- flash attention v2: paired q-tiles, grid (4, 64, 3), 256 thr ------------
__global__ __launch_bounds__(256, 3) void attn_kernel(const u16* __restrict__ qb,
    const u16* __restrict__ kb, const u16* __restrict__ vTb, u16* __restrict__ ob) {
  __shared__ __align__(16) u16 Ks[2][4096];
  __shared__ __align__(16) u16 Vs[2][4096];   // V^T [d][k], chunk-XOR swizzled
  __shared__ __align__(16) u16 Ps[4][1024];   // per-wave [16 q][64 k], chunk-XOR swizzled
  int a = blockIdx.x, bh = blockIdx.y, br = blockIdx.z;
  int b = bh >> 3, h = bh & 7;
  const u16* q  = qb + (size_t)br*Mm*Dm;
  const u16* k  = kb + (size_t)br*Mm*Dm;
  const u16* vT = vTb + (((size_t)br << 21) + ((size_t)bh << 15));  // [br][bh][64][512]
  u16* o = ob + (size_t)br*Mm*Dm;
  int tid = threadIdx.x, lane = tid & 63, wid = tid >> 6;
  int r16 = lane & 15, g = lane >> 4;
  size_t rowbase = (size_t)b * Sm;
  int qt[2] = {7 - a, a};
  int nkt = qt[0] + 1;

  bf16x8 qa[2][2];
  #pragma unroll
  for (int t2 = 0; t2 < 2; ++t2)
    #pragma unroll
    for (int c = 0; c < 2; ++c)
      qa[t2][c] = *(const bf16x8*)(q + (rowbase + qt[t2]*64 + wid*16 + r16)*Dm + h*64 + c*32 + g*8);

  float m_[2][4], l_[2][4];
  fx4 accO[2][4] = {};
  #pragma unroll
  for (int t2 = 0; t2 < 2; ++t2)
    #pragma unroll
    for (int r = 0; r < 4; ++r) { m_[t2][r] = -3.0e38f; l_[t2][r] = 0.f; }

  auto stage = [&](int kt, int bufi) {
    #pragma unroll
    for (int it = 0; it < 2; ++it) {
      int zb = wid*128 + it*64;
      int zz = zb + lane;
      int row = zz >> 3, c = (zz & 7) ^ (row & 7);
      gload16(k + (rowbase + kt*64 + row)*Dm + h*64 + c*8, &Ks[bufi][zb * 8]);
      gload16(vT + ((size_t)row << 9) + kt*64 + c*8, &Vs[bufi][zb * 8]);
    }
  };
  stage(0, 0);
  __syncthreads();

  for (int kt = 0; kt < nkt; ++kt) {
    int cur = kt & 1;
    if (kt + 1 < nkt) stage(kt + 1, cur ^ 1);
    #pragma unroll
    for (int t2 = 0; t2 < 2; ++t2) {
      if (t2 == 0 || kt <= qt[1]) {
        fx4 sacc[4] = {};
        #pragma unroll
        for (int c = 0; c < 2; ++c)
          #pragma unroll
          for (int n = 0; n < 4; ++n) {
            int row = n*16 + r16;
            bf16x8 kf = *(const bf16x8*)(&Ks[cur][(row << 6) + (((c*4 + g) ^ (row & 7)) << 3)]);
            sacc[n] = __builtin_amdgcn_mfma_f32_16x16x32_bf16(qa[t2][c], kf, sacc[n], 0, 0, 0);
          }
        float sv[4][4];
        bool diag = (kt == qt[t2]);
        #pragma unroll
        for (int n = 0; n < 4; ++n)
          #pragma unroll
          for (int r = 0; r < 4; ++r) {
            float s = sacc[n][r] * 0.125f;
            if (diag && (n*16 + r16 > wid*16 + g*4 + r)) s = -3.0e38f;
            sv[n][r] = s;
          }
        #pragma unroll
        for (int r = 0; r < 4; ++r) {
          float rm = fmaxf(fmaxf(sv[0][r], sv[1][r]), fmaxf(sv[2][r], sv[3][r]));
          #pragma unroll
          for (int off = 1; off < 16; off <<= 1) rm = fmaxf(rm, __shfl_xor(rm, off, 64));
          float mnew = fmaxf(m_[t2][r], rm);
          float corr = __expf(m_[t2][r] - mnew);
          m_[t2][r] = mnew;
          float rs = 0.f;
          #pragma unroll
          for (int n = 0; n < 4; ++n) { float p = __expf(sv[n][r] - mnew); sv[n][r] = p; rs += p; }
          #pragma unroll
          for (int off = 1; off < 16; off <<= 1) rs += __shfl_xor(rs, off, 64);
          l_[t2][r] = l_[t2][r]*corr + rs;
          #pragma unroll
          for (int n = 0; n < 4; ++n) accO[t2][n][r] *= corr;
        }
        #pragma unroll
        for (int n = 0; n < 4; ++n)
          #pragma unroll
          for (int r = 0; r < 4; ++r) {
            int qq = g*4 + r;
            Ps[wid][(qq << 6) + (((n*2 + (r16 >> 3)) ^ (qq & 7)) << 3) + (r16 & 7)] = f2b(sv[n][r]);
          }
        #pragma unroll
        for (int kk = 0; kk < 2; ++kk) {
          bf16x8 pa = *(const bf16x8*)(&Ps[wid][(r16 << 6) + (((kk*4 + g) ^ (r16 & 7)) << 3)]);
          #pragma unroll
          for (int n = 0; n < 4; ++n) {
            int row = n*16 + r16;
            bf16x8 vf = *(const bf16x8*)(&Vs[cur][(row << 6) + (((kk*4 + g) ^ (row & 7)) << 3)]);
            accO[t2][n] = __builtin_amdgcn_mfma_f32_16x16x32_bf16(pa, vf, accO[t2][n], 0, 0, 0);
          }
        }
      }
    }
    __syncthreads();
  }
  #pragma unroll
  for (int t2 = 0; t2 < 2; ++t2)
    #pragma unroll
    for (int n = 0; n < 4; ++n)
      #pragma unroll
      for (int r = 0; r < 4; ++r) {
        int qrow = qt[t2]*64 + wid*16 + g*4 + r;
        o[(rowbase + qrow)*Dm + h*64 + n*16 + r16] = f2b(accO[t2][n][r] / l_[t2][r]);
      }
}

// ---------------- host ----------------
extern "C" void kernel_launch(void* const* d_in, const int* in_sizes, int n_in,
                              void* d_out, int out_size, void* d_ws, size_t ws_size,
                              hipStream_t stream) {
  const float* x_in = (const float*)d_in[0];
  const float* Wq1 = (const float*)d_in[1];
  const float* Wk1 = (const float*)d_in[2];
  const float* Wq3 = (const float*)d_in[3];
  const float* Wk3 = (const float*)d_in[4];
  const float* Wq5 = (const float*)d_in[5];
  const float* Wk5 = (const float*)d_in[6];
  const float* bq  = (const float*)d_in[7];
  const float* bk  = (const float*)d_in[8];
  const float* Wv  = (const float*)d_in[9];
  const float* bv  = (const float*)d_in[10];
  const float* Wo  = (const float*)d_in[11];
  const float* bo  = (const float*)d_in[12];
  const float* W1  = (const float*)d_in[13];
  const float* b1  = (const float*)d_in[14];
  const float* W2  = (const float*)d_in[15];
  const float* b2  = (const float*)d_in[16];
  const float* ln1g = (const float*)d_in[17];
  const float* ln1b = (const float*)d_in[18];
  const float* ln2g = (const float*)d_in[19];
  const float* ln2b = (const float*)d_in[20];

  char* ws = (char*)d_ws;
  size_t off = 0;
  auto alloc = [&](size_t bytes) { void* p = ws + off; off += (bytes + 255) & ~(size_t)255; return p; };
  float* x_f32 = (float*)alloc((size_t)Mm*Dm*4);
  u16*   xb    = (u16*)  alloc((size_t)Mm*Dm*2);
  u16*   qbuf  = (u16*)  alloc((size_t)3*Mm*Dm*2);
  u16*   kbuf  = (u16*)  alloc((size_t)3*Mm*Dm*2);
  u16*   vT    = (u16*)  alloc((size_t)3*Mm*Dm*2);   // [br][bh][d 64][s 512]
  u16*   obuf  = (u16*)  alloc((size_t)3*Mm*Dm*2);
  u16*   avgb  = (u16*)  alloc((size_t)Mm*Dm*2);
  float* pre   = (float*)alloc((size_t)Mm*Dm*4);
  float* out1f = (float*)alloc((size_t)Mm*Dm*4);
  u16*   out1b = (u16*)  alloc((size_t)Mm*Dm*2);
  u16*   midb  = (u16*)  alloc((size_t)Mm*Fm*2);
  u16*   packed= (u16*)  alloc((size_t)960*8192*2);
  u16*   zpad  = (u16*)  alloc(1024);

  cast_bf16_kernel<<<2048, 256, 0, stream>>>(x_in, xb, zpad);
  for (int l = 0; l < Lm; ++l) {
    const float* xs = (l == 0) ? x_in : x_f32;
    prep_kernel<<<960, 256, 0, stream>>>(packed, Wq1, Wq3, Wq5, Wk1, Wk3, Wk5,
                                         Wv, Wo, W1, W2, l);
    conv_all<<<1152, 256, 0, stream>>>(
        xb, packed, bq, bk, bv, qbuf, kbuf, vT, l, zpad);
    attn_kernel<<<dim3(4, 64, 3), 256, 0, stream>>>(qbuf, kbuf, vT, obuf);
    avg3_kernel<<<2048, 256, 0, stream>>>(obuf, avgb);
    gemm_dense<2, 64, 4, 3><<<dim3(64, 4), 256, 0, stream>>>(
        avgb, 512, 512, packed + ((size_t)672 << 13), bo + (size_t)l*Dm, xs, nullptr, pre, 512);
    ln_kernel<<<4096, 64, 0, stream>>>(pre, nullptr, ln1g + (size_t)l*Dm, ln1b + (size_t)l*Dm,
                                       out1f, out1b);
    gemm_dense<1, 128, 2, 3><<<dim3(32, 16), 256, 0, stream>>>(
        out1b, 512, 512, packed + ((size_t)704 << 13), b1 + (size_t)l*Fm, nullptr, midb, nullptr, 2048);
    gemm_dense<2, 64, 4, 3><<<dim3(64, 4), 256, 0, stream>>>(
        midb, 2048, 2048, packed + ((size_t)832 << 13), b2 + (size_t)l*Dm, out1f, nullptr, pre, 512);
    float* lnout = (l == Lm-1) ? (float*)d_out : x_f32;
    ln_kernel<<<4096, 64, 0, stream>>>(pre, nullptr, ln2g + (size_t)l*Dm, ln2b + (size_t)l*Dm,
                                       lnout, xb);
  }
}

// Round 9
// 620.369 us; speedup vs baseline: 1.1069x; 1.1069x over previous
//
#include <hip/hip_runtime.h>
#include <cstdint>
#include <cstddef>

#define Dm 512
#define Sm 512
#define Bm 8
#define Hm 8
#define Fm 2048
#define Mm 4096   // B*S
#define Lm 4

typedef __bf16 bf16x8 __attribute__((ext_vector_type(8)));
typedef float  fx4    __attribute__((ext_vector_type(4)));
typedef float  fx2    __attribute__((ext_vector_type(2)));
typedef unsigned short u16;
typedef unsigned short u16x4 __attribute__((ext_vector_type(4)));
typedef short s16x8 __attribute__((ext_vector_type(8)));

__device__ __forceinline__ u16 f2b(float f) {
  union { float f; uint32_t u; } v; v.f = f;
  uint32_t u = v.u;
  return (u16)((u + 0x7fffu + ((u >> 16) & 1u)) >> 16);  // RNE
}
__device__ __forceinline__ float b2f(u16 h) {
  union { uint32_t u; float f; } v; v.u = ((uint32_t)h) << 16;
  return v.f;
}

__device__ __forceinline__ void gload16(const void* g, void* l) {
  __builtin_amdgcn_global_load_lds(
      (const __attribute__((address_space(1))) void*)g,
      (__attribute__((address_space(3))) void*)l, 16, 0, 0);
}

// counted vmcnt wait — drains the A-DMA (oldest) while leaving B prefetch in flight
template<int N>
__device__ __forceinline__ void vwait() {
  if constexpr (N == 4)      asm volatile("s_waitcnt vmcnt(4)" ::: "memory");
  else if constexpr (N == 8) asm volatile("s_waitcnt vmcnt(8)" ::: "memory");
  else                       asm volatile("s_waitcnt vmcnt(0)" ::: "memory");
}

// ---------------- elementwise ----------------
__global__ void cast_bf16_kernel(const float* __restrict__ in, u16* __restrict__ out,
                                 u16* __restrict__ zpad) {
  int i = (blockIdx.x * 256 + threadIdx.x) * 4;
  fx4 v = *(const fx4*)(in + i);
  u16x4 o;
  #pragma unroll
  for (int j = 0; j < 4; ++j) o[j] = f2b(v[j]);
  *(u16x4*)(out + i) = o;
  if (blockIdx.x == 0) { zpad[threadIdx.x] = 0; zpad[threadIdx.x + 256] = 0; }
}

__global__ void avg3_kernel(const u16* __restrict__ o3, u16* __restrict__ out) {
  int i = (blockIdx.x * 256 + threadIdx.x) * 4;
  u16x4 a = *(const u16x4*)(o3 + i);
  u16x4 b = *(const u16x4*)(o3 + (size_t)Mm*Dm + i);
  u16x4 c = *(const u16x4*)(o3 + (size_t)2*Mm*Dm + i);
  u16x4 r;
  #pragma unroll
  for (int j = 0; j < 4; ++j)
    r[j] = f2b((b2f(a[j]) + b2f(b[j]) + b2f(c[j])) * (1.f/3.f));
  *(u16x4*)(out + i) = r;
}

// ---------------- layernorm (1 wave / row) ----------------
__global__ void ln_kernel(const float* __restrict__ in, const float* __restrict__ gam,
                          const float* __restrict__ bet, float* __restrict__ outf,
                          u16* __restrict__ outb) {
  int row = blockIdx.x;
  int t = threadIdx.x;  // 64
  const float* x = in + (size_t)row * Dm;
  fx4 v0 = *(const fx4*)(x + t*4);
  fx4 v1 = *(const fx4*)(x + 256 + t*4);
  float s = 0.f, sq = 0.f;
  #pragma unroll
  for (int j = 0; j < 4; ++j) { s += v0[j] + v1[j]; sq += v0[j]*v0[j] + v1[j]*v1[j]; }
  #pragma unroll
  for (int off = 1; off < 64; off <<= 1) { s += __shfl_xor(s, off, 64); sq += __shfl_xor(sq, off, 64); }
  float mu  = s * (1.f/Dm);
  float var = sq * (1.f/Dm) - mu*mu;
  float rstd = rsqrtf(var + 1e-6f);
  fx4 g0 = *(const fx4*)(gam + t*4), g1 = *(const fx4*)(gam + 256 + t*4);
  fx4 b0 = *(const fx4*)(bet + t*4), b1 = *(const fx4*)(bet + 256 + t*4);
  float* of = outf + (size_t)row*Dm;
  u16*   ob = outb + (size_t)row*Dm;
  fx4 y0, y1; u16x4 h0, h1;
  #pragma unroll
  for (int j = 0; j < 4; ++j) {
    y0[j] = (v0[j]-mu)*rstd*g0[j] + b0[j];
    y1[j] = (v1[j]-mu)*rstd*g1[j] + b1[j];
    h0[j] = f2b(y0[j]); h1[j] = f2b(y1[j]);
  }
  *(fx4*)(of + t*4) = y0; *(fx4*)(of + 256 + t*4) = y1;
  *(u16x4*)(ob + t*4) = h0; *(u16x4*)(ob + 256 + t*4) = h1;
}

// ---------------- weight prep: fp32 [K][N] -> bf16 pre-swizzled 128x64 fragment-tile images
#define TST 130
__global__ void prep_kernel(u16* __restrict__ packed,
    const float* __restrict__ Wq1, const float* __restrict__ Wq3, const float* __restrict__ Wq5,
    const float* __restrict__ Wk1, const float* __restrict__ Wk3, const float* __restrict__ Wk5,
    const float* __restrict__ Wv,  const float* __restrict__ Wo,
    const float* __restrict__ W1,  const float* __restrict__ W2, int layer) {
  __shared__ float T[64 * TST];
  constexpr int t0[13] = {0,32,128,288,320,416,576,608,640,672,704,832,960};
  int bid = blockIdx.x;
  int seg = 0;
  while (bid >= t0[seg+1]) ++seg;
  int local = bid - t0[seg];
  const float* src; int K, N;
  switch (seg) {
    case 0:  src = Wq1 + (size_t)layer*512*512;   K = 512;  N = 512;  break;
    case 1:  src = Wq3 + (size_t)layer*3*512*512; K = 1536; N = 512;  break;
    case 2:  src = Wq5 + (size_t)layer*5*512*512; K = 2560; N = 512;  break;
    case 3:  src = Wk1 + (size_t)layer*512*512;   K = 512;  N = 512;  break;
    case 4:  src = Wk3 + (size_t)layer*3*512*512; K = 1536; N = 512;  break;
    case 5:  src = Wk5 + (size_t)layer*5*512*512; K = 2560; N = 512;  break;
    case 6:  src = Wv + (size_t)(layer*3+0)*512*512; K = 512; N = 512; break;
    case 7:  src = Wv + (size_t)(layer*3+1)*512*512; K = 512; N = 512; break;
    case 8:  src = Wv + (size_t)(layer*3+2)*512*512; K = 512; N = 512; break;
    case 9:  src = Wo + (size_t)layer*512*512;    K = 512;  N = 512;  break;
    case 10: src = W1 + (size_t)layer*512*2048;   K = 512;  N = 2048; break;
    default: src = W2 + (size_t)layer*2048*512;   K = 2048; N = 512;  break;
  }
  int KT = K >> 6;
  int ntile = local / KT, ktile = local - ntile*KT;
  const float* sb = src + (size_t)(ktile*64)*N + ntile*128;
  int tid = threadIdx.x;
  #pragma unroll
  for (int i = 0; i < 16; ++i) {                 // 4096 float2 chunks, coalesced
    int idx = i*256 + tid;
    int row = idx >> 6, col2 = (idx & 63) * 2;
    fx2 v = *(const fx2*)(sb + (size_t)row*N + col2);
    *(fx2*)(&T[row*TST + col2]) = v;
  }
  __syncthreads();
  u16* dst = packed + ((size_t)bid << 13);
  #pragma unroll
  for (int j = 0; j < 4; ++j) {
    int z = j*256 + tid;
    int row = z >> 3;
    int c = (z & 7) ^ (row & 7);
    s16x8 o;
    #pragma unroll
    for (int e = 0; e < 8; ++e) o[e] = (short)f2b(T[(c*8 + e)*TST + row]);
    *(s16x8*)(dst + z*8) = o;
  }
}

// ======== pipelined K-step macro: B reg-prefetched 1 step ahead, A-DMA drained by
// counted vmcnt (= 2*NRv, leaves B in flight), raw s_barrier. Static LDS buf indices. ====
#define GEMM_STEP(IDX, CB, NB, BC, BN, NRv, NW)                                   \
  {                                                                              \
    bool hn = (IDX) + 1 < ntiles;                                                \
    if (hn) {                                                                    \
      stageA(NB);                                                                \
      ++skt; if (skt == KTt) { skt = 0; ++st; }                                  \
      const u16* wtn = WtN + ((size_t)((IDX) + 1) << 13);                        \
      _Pragma("unroll")                                                          \
      for (int kk = 0; kk < 2; ++kk)                                             \
        _Pragma("unroll")                                                        \
        for (int n = 0; n < NRv; ++n) {                                          \
          int row = wn*(NRv*16) + n*16 + r16;                                    \
          BN[kk][n] = *(const bf16x8*)(wtn + (row << 6) + (((kk*4 + g) ^ (row & 7)) << 3)); \
        }                                                                        \
    }                                                                            \
    bf16x8 a_[2][4];                                                             \
    _Pragma("unroll")                                                            \
    for (int kk = 0; kk < 2; ++kk)                                               \
      _Pragma("unroll")                                                          \
      for (int m = 0; m < 4; ++m) {                                              \
        int row = wm*64 + m*16 + r16;                                            \
        a_[kk][m] = *(const bf16x8*)(&As[CB][(row << 6) + (((kk*4 + g) ^ (row & 7)) << 3)]); \
      }                                                                          \
    __builtin_amdgcn_s_setprio(1);                                               \
    _Pragma("unroll")                                                            \
    for (int kk = 0; kk < 2; ++kk)                                               \
      _Pragma("unroll")                                                          \
      for (int m = 0; m < 4; ++m)                                                \
        _Pragma("unroll")                                                        \
        for (int n = 0; n < NRv; ++n)                                            \
          acc[m][n] = __builtin_amdgcn_mfma_f32_16x16x32_bf16(a_[kk][m], BC[kk][n], acc[m][n], 0, 0, 0); \
    __builtin_amdgcn_s_setprio(0);                                               \
    vwait<2*NRv>();                                                              \
    __builtin_amdgcn_s_barrier();                                                \
  }

// ---------------- conv_all: heaviest-first 1D grid, reg-prefetch pipeline ----------------
// grid 1152. BM=128, BN=128, BK=64. A dbuf in LDS (32KB); B direct-from-global, 1 step ahead.
__global__ __launch_bounds__(256, 2) void conv_all(const u16* __restrict__ xb,
    const u16* __restrict__ packed,
    const float* __restrict__ bq, const float* __restrict__ bk, const float* __restrict__ bv,
    u16* __restrict__ qb, u16* __restrict__ kb, u16* __restrict__ vT, int layer,
    const u16* __restrict__ zpad) {
  __shared__ __align__(16) u16 As[2][8192];
  constexpr int t0c[9]   = {0,32,128,288,320,416,576,608,640};
  constexpr int tapsc[9] = {1,3,5,1,3,5,1,1,1};
  constexpr int order[9] = {2,5,1,4,0,3,6,7,8};   // Q5,K5,Q3,K3,Q1,K1,V0,V1,V2
  int bid = blockIdx.x;
  int unit = order[bid >> 7];
  int local = bid & 127;
  int mtile = local >> 2, ntile = local & 3;
  int taps = tapsc[unit];
  int brow = mtile * 128, bcol = ntile * 128;
  int tid = threadIdx.x, lane = tid & 63, wid = tid >> 6;
  int wm = wid >> 1, wn = wid & 1;
  int r16 = lane & 15, g = lane >> 4;
  const u16* WtN = packed + ((size_t)(t0c[unit] + ntile * taps * 8) << 13);
  fx4 acc[4][4] = {};
  int ntiles = taps * 8;
  const int KTt = 8;
  int st = 0, skt = 0;
  auto stageA = [&](int bufi) {
    int shift = taps - 1 - st;
    int c0 = skt << 6;
    #pragma unroll
    for (int j = 0; j < 4; ++j) {        // A: 128x64 bf16, 4 DMA/thread (issued FIRST)
      int zb = wid*256 + j*64;
      int zz = zb + lane;
      int row = zz >> 3, c = (zz & 7) ^ (row & 7);
      int s = (brow + row) & (Sm - 1);
      const u16* src = (s >= shift) ? (xb + (size_t)(brow + row - shift)*Dm + c0 + c*8) : zpad;
      gload16(src, &As[bufi][zb * 8]);
    }
  };
  bf16x8 bA[2][4], bB[2][4];
  stageA(0);
  ++skt; if (skt == KTt) { skt = 0; ++st; }
  #pragma unroll
  for (int kk = 0; kk < 2; ++kk)
    #pragma unroll
    for (int n = 0; n < 4; ++n) {
      int row = wn*64 + n*16 + r16;
      bA[kk][n] = *(const bf16x8*)(WtN + (row << 6) + (((kk*4 + g) ^ (row & 7)) << 3));
    }
  __syncthreads();
  for (int base = 0; base < ntiles; base += 2) {
    GEMM_STEP(base,     0, 1, bA, bB, 4, 2)
    GEMM_STEP(base + 1, 1, 0, bB, bA, 4, 2)
  }
  // epilogue (runtime branch, uniform per block)
  const float* bias; u16* outp;
  if (unit < 3)      { bias = bq + (size_t)(layer*3 + unit)*Dm;   outp = qb + (size_t)unit*Mm*Dm; }
  else if (unit < 6) { bias = bk + (size_t)(layer*3 + unit-3)*Dm; outp = kb + (size_t)(unit-3)*Mm*Dm; }
  else               { bias = bv + (size_t)(layer*3 + unit-6)*Dm; outp = vT + ((size_t)(unit-6) << 21); }
  if (unit < 6) {
    #pragma unroll
    for (int m = 0; m < 4; ++m) {
      int row0 = brow + wm*64 + m*16 + g*4;
      #pragma unroll
      for (int n = 0; n < 4; ++n) {
        int col = bcol + wn*64 + n*16 + r16;
        float bv_ = bias[col];
        #pragma unroll
        for (int r = 0; r < 4; ++r)
          outp[(size_t)(row0 + r)*Dm + col] = f2b(acc[m][n][r] + bv_);
      }
    }
  } else {
    #pragma unroll
    for (int m = 0; m < 4; ++m) {
      int row0 = brow + wm*64 + m*16 + g*4;
      int bidx = row0 >> 9, spos = row0 & 511;
      #pragma unroll
      for (int n = 0; n < 4; ++n) {
        int col = bcol + wn*64 + n*16 + r16;
        int hh = col >> 6, dd = col & 63;
        float bv_ = bias[col];
        u16x4 pk;
        #pragma unroll
        for (int r = 0; r < 4; ++r) pk[r] = f2b(acc[m][n][r] + bv_);
        *(u16x4*)(outp + (((size_t)(bidx*8 + hh)*64 + dd) << 9) + spos) = pk;
      }
    }
  }
}

// ---------------- unified GEMM core: same reg-prefetch pipeline ----------------
// MODE 0: bf16 out; MODE 1: bf16 relu out; MODE 2: f32 out + residual
template<int MODE, int BMt, int WN, bool CAUSAL>
__device__ __forceinline__ void gemm_core(const u16* __restrict__ A, int lda, int Ktap, int taps,
    const u16* __restrict__ Wt, const float* __restrict__ bias, const float* __restrict__ res,
    u16* __restrict__ outb, float* __restrict__ outf, int N, const u16* __restrict__ zpad) {
  constexpr int NR = 128 / (16 * WN);
  constexpr int AD = BMt / 32;    // A DMA issues / iter
  __shared__ __align__(16) u16 As[2][BMt * 64];
  int tid = threadIdx.x, lane = tid & 63, wid = tid >> 6;
  int wm = (WN == 2) ? (wid >> 1) : 0;
  int wn = (WN == 2) ? (wid & 1) : wid;
  int r16 = lane & 15, g = lane >> 4;
  int brow = blockIdx.x * BMt, bcol = blockIdx.y * 128;
  const int KTt = Ktap >> 6;
  const u16* WtN = Wt + ((size_t)(blockIdx.y * taps * KTt) << 13);
  fx4 acc[4][NR] = {};
  int ntiles = taps * KTt;
  int st = 0, skt = 0;
  auto stageA = [&](int bufi) {
    int shift = taps - 1 - st;
    int c0 = skt << 6;
    #pragma unroll
    for (int j = 0; j < AD; ++j) {
      int zb = wid*(BMt*2) + j*64;
      int zz = zb + lane;
      int row = zz >> 3, c = (zz & 7) ^ (row & 7);
      const u16* src;
      if (CAUSAL) {
        int s = (brow + row) & (Sm - 1);
        src = (s >= shift) ? (A + (size_t)(brow + row - shift)*lda + c0 + c*8) : zpad;
      } else {
        src = A + (size_t)(brow + row)*lda + c0 + c*8;
      }
      gload16(src, &As[bufi][zb * 8]);
    }
  };
  bf16x8 bA[2][NR], bB[2][NR];
  stageA(0);
  ++skt; if (skt == KTt) { skt = 0; ++st; }
  #pragma unroll
  for (int kk = 0; kk < 2; ++kk)
    #pragma unroll
    for (int n = 0; n < NR; ++n) {
      int row = wn*(NR*16) + n*16 + r16;
      bA[kk][n] = *(const bf16x8*)(WtN + (row << 6) + (((kk*4 + g) ^ (row & 7)) << 3));
    }
  __syncthreads();
  for (int base = 0; base < ntiles; base += 2) {
    GEMM_STEP(base,     0, 1, bA, bB, NR, WN)
    GEMM_STEP(base + 1, 1, 0, bB, bA, NR, WN)
  }
  #pragma unroll
  for (int m = 0; m < 4; ++m) {
    int row0 = brow + wm*64 + m*16 + g*4;
    #pragma unroll
    for (int n = 0; n < NR; ++n) {
      int col = bcol + wn*(NR*16) + n*16 + r16;
      float bv_ = bias[col];
      #pragma unroll
      for (int r = 0; r < 4; ++r) {
        size_t idx = (size_t)(row0 + r)*N + col;
        float v = acc[m][n][r] + bv_;
        if (MODE == 0)      outb[idx] = f2b(v);
        else if (MODE == 1) outb[idx] = f2b(fmaxf(v, 0.f));
        else                outf[idx] = v + res[idx];
      }
    }
  }
}

template<int MODE, int BMt, int WN, int LB>
__global__ __launch_bounds__(256, LB) void gemm_dense(const u16* __restrict__ A, int lda, int K,
    const u16* __restrict__ Wt, const float* __restrict__ bias, const float* __restrict__ res,
    u16* __restrict__ outb, float* __restrict__ outf, int N) {
  gemm_core<MODE, BMt, WN, false>(A, lda, K, 1, Wt, bias, res, outb, outf, N, nullptr);
}

// ---------------- flash attention v2: paired q-tiles, grid (4, 64, 3), 256 thr ------------
__global__ __launch_bounds__(256, 3) void attn_kernel(const u16* __restrict__ qb,
    const u16* __restrict__ kb, const u16* __restrict__ vTb, u16* __restrict__ ob) {
  __shared__ __align__(16) u16 Ks[2][4096];
  __shared__ __align__(16) u16 Vs[2][4096];   // V^T [d][k], chunk-XOR swizzled
  __shared__ __align__(16) u16 Ps[4][1024];   // per-wave [16 q][64 k], chunk-XOR swizzled
  int a = blockIdx.x, bh = blockIdx.y, br = blockIdx.z;
  int b = bh >> 3, h = bh & 7;
  const u16* q  = qb + (size_t)br*Mm*Dm;
  const u16* k  = kb + (size_t)br*Mm*Dm;
  const u16* vT = vTb + (((size_t)br << 21) + ((size_t)bh << 15));  // [br][bh][64][512]
  u16* o = ob + (size_t)br*Mm*Dm;
  int tid = threadIdx.x, lane = tid & 63, wid = tid >> 6;
  int r16 = lane & 15, g = lane >> 4;
  size_t rowbase = (size_t)b * Sm;
  int qt[2] = {7 - a, a};
  int nkt = qt[0] + 1;

  bf16x8 qa[2][2];
  #pragma unroll
  for (int t2 = 0; t2 < 2; ++t2)
    #pragma unroll
    for (int c = 0; c < 2; ++c)
      qa[t2][c] = *(const bf16x8*)(q + (rowbase + qt[t2]*64 + wid*16 + r16)*Dm + h*64 + c*32 + g*8);

  float m_[2][4], l_[2][4];
  fx4 accO[2][4] = {};
  #pragma unroll
  for (int t2 = 0; t2 < 2; ++t2)
    #pragma unroll
    for (int r = 0; r < 4; ++r) { m_[t2][r] = -3.0e38f; l_[t2][r] = 0.f; }

  auto stage = [&](int kt, int bufi) {
    #pragma unroll
    for (int it = 0; it < 2; ++it) {
      int zb = wid*128 + it*64;
      int zz = zb + lane;
      int row = zz >> 3, c = (zz & 7) ^ (row & 7);
      gload16(k + (rowbase + kt*64 + row)*Dm + h*64 + c*8, &Ks[bufi][zb * 8]);
      gload16(vT + ((size_t)row << 9) + kt*64 + c*8, &Vs[bufi][zb * 8]);
    }
  };
  stage(0, 0);
  __syncthreads();

  for (int kt = 0; kt < nkt; ++kt) {
    int cur = kt & 1;
    if (kt + 1 < nkt) stage(kt + 1, cur ^ 1);
    #pragma unroll
    for (int t2 = 0; t2 < 2; ++t2) {
      if (t2 == 0 || kt <= qt[1]) {
        fx4 sacc[4] = {};
        #pragma unroll
        for (int c = 0; c < 2; ++c)
          #pragma unroll
          for (int n = 0; n < 4; ++n) {
            int row = n*16 + r16;
            bf16x8 kf = *(const bf16x8*)(&Ks[cur][(row << 6) + (((c*4 + g) ^ (row & 7)) << 3)]);
            sacc[n] = __builtin_amdgcn_mfma_f32_16x16x32_bf16(qa[t2][c], kf, sacc[n], 0, 0, 0);
          }
        float sv[4][4];
        bool diag = (kt == qt[t2]);
        #pragma unroll
        for (int n = 0; n < 4; ++n)
          #pragma unroll
          for (int r = 0; r < 4; ++r) {
            float s = sacc[n][r] * 0.125f;
            if (diag && (n*16 + r16 > wid*16 + g*4 + r)) s = -3.0e38f;
            sv[n][r] = s;
          }
        #pragma unroll
        for (int r = 0; r < 4; ++r) {
          float rm = fmaxf(fmaxf(sv[0][r], sv[1][r]), fmaxf(sv[2][r], sv[3][r]));
          #pragma unroll
          for (int off = 1; off < 16; off <<= 1) rm = fmaxf(rm, __shfl_xor(rm, off, 64));
          float mnew = fmaxf(m_[t2][r], rm);
          float corr = __expf(m_[t2][r] - mnew);
          m_[t2][r] = mnew;
          float rs = 0.f;
          #pragma unroll
          for (int n = 0; n < 4; ++n) { float p = __expf(sv[n][r] - mnew); sv[n][r] = p; rs += p; }
          #pragma unroll
          for (int off = 1; off < 16; off <<= 1) rs += __shfl_xor(rs, off, 64);
          l_[t2][r] = l_[t2][r]*corr + rs;
          #pragma unroll
          for (int n = 0; n < 4; ++n) accO[t2][n][r] *= corr;
        }
        #pragma unroll
        for (int n = 0; n < 4; ++n)
          #pragma unroll
          for (int r = 0; r < 4; ++r) {
            int qq = g*4 + r;
            Ps[wid][(qq << 6) + (((n*2 + (r16 >> 3)) ^ (qq & 7)) << 3) + (r16 & 7)] = f2b(sv[n][r]);
          }
        #pragma unroll
        for (int kk = 0; kk < 2; ++kk) {
          bf16x8 pa = *(const bf16x8*)(&Ps[wid][(r16 << 6) + (((kk*4 + g) ^ (r16 & 7)) << 3)]);
          #pragma unroll
          for (int n = 0; n < 4; ++n) {
            int row = n*16 + r16;
            bf16x8 vf = *(const bf16x8*)(&Vs[cur][(row << 6) + (((kk*4 + g) ^ (row & 7)) << 3)]);
            accO[t2][n] = __builtin_amdgcn_mfma_f32_16x16x32_bf16(pa, vf, accO[t2][n], 0, 0, 0);
          }
        }
      }
    }
    __syncthreads();
  }
  #pragma unroll
  for (int t2 = 0; t2 < 2; ++t2)
    #pragma unroll
    for (int n = 0; n < 4; ++n)
      #pragma unroll
      for (int r = 0; r < 4; ++r) {
        int qrow = qt[t2]*64 + wid*16 + g*4 + r;
        o[(rowbase + qrow)*Dm + h*64 + n*16 + r16] = f2b(accO[t2][n][r] / l_[t2][r]);
      }
}

// ---------------- host ----------------
extern "C" void kernel_launch(void* const* d_in, const int* in_sizes, int n_in,
                              void* d_out, int out_size, void* d_ws, size_t ws_size,
                              hipStream_t stream) {
  const float* x_in = (const float*)d_in[0];
  const float* Wq1 = (const float*)d_in[1];
  const float* Wk1 = (const float*)d_in[2];
  const float* Wq3 = (const float*)d_in[3];
  const float* Wk3 = (const float*)d_in[4];
  const float* Wq5 = (const float*)d_in[5];
  const float* Wk5 = (const float*)d_in[6];
  const float* bq  = (const float*)d_in[7];
  const float* bk  = (const float*)d_in[8];
  const float* Wv  = (const float*)d_in[9];
  const float* bv  = (const float*)d_in[10];
  const float* Wo  = (const float*)d_in[11];
  const float* bo  = (const float*)d_in[12];
  const float* W1  = (const float*)d_in[13];
  const float* b1  = (const float*)d_in[14];
  const float* W2  = (const float*)d_in[15];
  const float* b2  = (const float*)d_in[16];
  const float* ln1g = (const float*)d_in[17];
  const float* ln1b = (const float*)d_in[18];
  const float* ln2g = (const float*)d_in[19];
  const float* ln2b = (const float*)d_in[20];

  char* ws = (char*)d_ws;
  size_t off = 0;
  auto alloc = [&](size_t bytes) { void* p = ws + off; off += (bytes + 255) & ~(size_t)255; return p; };
  float* x_f32 = (float*)alloc((size_t)Mm*Dm*4);
  u16*   xb    = (u16*)  alloc((size_t)Mm*Dm*2);
  u16*   qbuf  = (u16*)  alloc((size_t)3*Mm*Dm*2);
  u16*   kbuf  = (u16*)  alloc((size_t)3*Mm*Dm*2);
  u16*   vT    = (u16*)  alloc((size_t)3*Mm*Dm*2);   // [br][bh][d 64][s 512]
  u16*   obuf  = (u16*)  alloc((size_t)3*Mm*Dm*2);
  u16*   avgb  = (u16*)  alloc((size_t)Mm*Dm*2);
  float* pre   = (float*)alloc((size_t)Mm*Dm*4);
  float* out1f = (float*)alloc((size_t)Mm*Dm*4);
  u16*   out1b = (u16*)  alloc((size_t)Mm*Dm*2);
  u16*   midb  = (u16*)  alloc((size_t)Mm*Fm*2);
  u16*   packed= (u16*)  alloc((size_t)960*8192*2);
  u16*   zpad  = (u16*)  alloc(1024);

  cast_bf16_kernel<<<2048, 256, 0, stream>>>(x_in, xb, zpad);
  for (int l = 0; l < Lm; ++l) {
    const float* xs = (l == 0) ? x_in : x_f32;
    prep_kernel<<<960, 256, 0, stream>>>(packed, Wq1, Wq3, Wq5, Wk1, Wk3, Wk5,
                                         Wv, Wo, W1, W2, l);
    conv_all<<<1152, 256, 0, stream>>>(
        xb, packed, bq, bk, bv, qbuf, kbuf, vT, l, zpad);
    attn_kernel<<<dim3(4, 64, 3), 256, 0, stream>>>(qbuf, kbuf, vT, obuf);
    avg3_kernel<<<2048, 256, 0, stream>>>(obuf, avgb);
    gemm_dense<2, 64, 4, 3><<<dim3(64, 4), 256, 0, stream>>>(
        avgb, 512, 512, packed + ((size_t)672 << 13), bo + (size_t)l*Dm, xs, nullptr, pre, 512);
    ln_kernel<<<4096, 64, 0, stream>>>(pre, ln1g + (size_t)l*Dm, ln1b + (size_t)l*Dm, out1f, out1b);
    gemm_dense<1, 128, 2, 2><<<dim3(32, 16), 256, 0, stream>>>(
        out1b, 512, 512, packed + ((size_t)704 << 13), b1 + (size_t)l*Fm, nullptr, midb, nullptr, 2048);
    gemm_dense<2, 64, 4, 3><<<dim3(64, 4), 256, 0, stream>>>(
        midb, 2048, 2048, packed + ((size_t)832 << 13), b2 + (size_t)l*Dm, out1f, nullptr, pre, 512);
    float* lnout = (l == Lm-1) ? (float*)d_out : x_f32;
    ln_kernel<<<4096, 64, 0, stream>>>(pre, ln2g + (size_t)l*Dm, ln2b + (size_t)l*Dm, lnout, xb);
  }
}